// Round 7
// baseline (88.176 us; speedup 1.0000x reference)
//
#include <hip/hip_runtime.h>

// Signature-kernel MMD, fused. R7 = R6 (verified layout) + three stall cuts:
//  - E-stream via DPP: eF(k) = wave_shr1(oF(k-1))  [binc[l-1][k-1-l] =
//    lane(l-1)'s O load of body k-1] -> 1 LDS read + 1 cvt per body (was 2+2).
//  - prefetch depth 8 bodies (~2 iters) so lgkm waits retire old loads.
//  - 2 waves/block, 1536 blocks -> 6 blocks/CU, finer dispatch granularity.
// Layout unchanged from R6: fp16 row-major binc, stride 66, zero-padded;
// out-of-window reads return 0 and/or are multiplied by exactly-zero state.

constexpr int S2  = 66;     // binc row stride (fp16 elems)
constexpr int PAD = 64;     // front pad (covers negative column offsets)
constexpr int BNA = 4368;   // per-pair buffer (PAD + 63*66 + rear pad, 16B-mult)

__global__ void zero_kernel(float* out) { out[0] = 0.0f; }

__device__ __forceinline__ float dpp_shr1(float v) {
    // result[l] = src[l-1], result[0] = 0
    return __builtin_bit_cast(float,
        __builtin_amdgcn_update_dpp(0, __builtin_bit_cast(int, v), 0x138, 0xF, 0xF, true));
}
__device__ __forceinline__ float dpp_shl1(float v) {
    // result[l] = src[l+1], result[63] = 0
    return __builtin_bit_cast(float,
        __builtin_amdgcn_update_dpp(0, __builtin_bit_cast(int, v), 0x130, 0xF, 0xF, true));
}
__device__ __forceinline__ float dot4(float4 a, float4 b) {
    return a.x * b.x + a.y * b.y + a.z * b.z + a.w * b.w;
}

// Two PDE substeps (antidiagonals 2k-1, 2k); ef/of are RAW binc values.
// State: p1E,p1O (diag d-1), p2E (E diag d-2), up2 (shr1 of O diag d-2),
// oP (previous body's of). Verified R3/R6.
#define BODY(ef, of) {                                 \
    float up1 = dpp_shr1(p1O);                         \
    float cE  = (up1 - up2) + p1E + up2 * (ef);        \
    float cO  = (p1E - p2E) + p1O + p2E * oP;          \
    float nu2 = up1, np2 = p1E;                        \
    p1E = cE; p1O = cO;                                \
    up1 = dpp_shr1(p1O);                               \
    cE  = (up1 - nu2) + p1E + nu2 * (ef);              \
    cO  = (p1E - np2) + p1O + np2 * (of);              \
    up2 = up1; p2E = p1E; p1E = cE; p1O = cO;          \
    oP  = (of); }

// Body with E derived from previous body's O float via DPP.
#define EBODY(foCur) {                                 \
    float eF = dpp_shr1(foPrev);                       \
    BODY(eF, foCur)                                    \
    foPrev = (foCur); }

__global__ __launch_bounds__(128) void sigpde_kernel(const float* __restrict__ x,
                                                     const float* __restrict__ y,
                                                     float* __restrict__ out) {
    __shared__ __align__(16) _Float16 binc[2][BNA];   // 17472 B
    __shared__ float4 xs[2][64];
    __shared__ float  xxs[2][64];
    __shared__ float  partial[2];

    const int lane = threadIdx.x & 63;
    const int wid  = threadIdx.x >> 6;
    const int p = blockIdx.x * 2 + wid;     // 0..3071
    const int g = p >> 10;                  // 0: xx, 1: xy, 2: yy
    const int q = p & 1023;
    const int a = q >> 5, b = q & 31;
    const float* Ab = (g == 2) ? y : x;
    const float* Bb = (g == 0) ? x : y;

    _Float16* bw = &binc[wid][0];

    float4 xa = ((const float4*)(Ab + a * 256))[lane];
    float4 yv = ((const float4*)(Bb + b * 256))[lane];
    xs[wid][lane]  = xa;
    xxs[wid][lane] = dot4(xa, xa);
    const float yy = dot4(yv, yv);

    {   // zero this wave's buffer (pads/gaps must be finite zeros)
        uint4* z = (uint4*)bw;
        const uint4 zz = {0u, 0u, 0u, 0u};
        for (int i = lane; i < BNA / 8; i += 64) z[i] = zz;
    }
    // No barrier: LDS below is wave-private; same-wave ds ordering via lgkmcnt.

    // Gram + double increments (column = lane), verified R6:
    // binc[u-1][lane] = 0.25*((G[u][l+1]-G[u][l]) - (G[u-1][l+1]-G[u-1][l]))
    float dp = 0.0f;
    #pragma unroll 4
    for (int u = 0; u < 64; ++u) {
        float4 xu = xs[wid][u];            // broadcast read
        float t = xxs[wid][u] + yy - 2.0f * dot4(xu, yv);
        float gv = __expf(-0.5f * t);
        float d = dpp_shl1(gv) - gv;
        if (u > 0) bw[PAD + (u - 1) * S2 + lane] = (_Float16)(0.25f * (d - dp));
        dp = d;
    }

    // Goursat PDE: lane owns rows iE=2l, iO=2l+1; body k = diagonals 2k-1,2k.
    // Single O-stream: body k loads oA[k-1] = binc[l][k-1-l]; the E factor is
    // eF(k) = shr1(oF(k-1)) (lane l-1's O value of the previous body).
    const int rO = (lane <= 62) ? lane : 62;
    const _Float16* oA = bw + PAD + rO * S2 - lane;

    float p1E = (lane == 0) ? 1.0f : 0.0f;  // diag 0 seed: K[0,0]=1
    float p1O = 0.0f, p2E = 0.0f, up2 = 0.0f, oP = 0.0f;
    float foPrev = 0.0f;                    // oF(0): out-of-window -> 0

    // warmup: bodies 1..4 converted; bodies 5..8 raw in flight
    float fo0 = (float)oA[0], fo1 = (float)oA[1], fo2 = (float)oA[2], fo3 = (float)oA[3];
    _Float16 h0 = oA[4], h1 = oA[5], h2 = oA[6], h3 = oA[7];

    for (int i = 0; i < 30; ++i) {          // bodies B..B+3, B = 1+4i (1..120)
        // prefetch bodies B+8..B+11 (indices 8+4i..11+4i <= 127, in-buffer)
        _Float16 n0 = oA[4 * i + 8], n1 = oA[4 * i + 9],
                 n2 = oA[4 * i + 10], n3 = oA[4 * i + 11];
        // convert bodies B+4..B+7 (loaded last iteration)
        float g0 = (float)h0, g1 = (float)h1, g2 = (float)h2, g3 = (float)h3;
        // compute bodies B..B+3
        EBODY(fo0) EBODY(fo1) EBODY(fo2) EBODY(fo3)
        // rotate pipeline
        fo0 = g0; fo1 = g1; fo2 = g2; fo3 = g3;
        h0 = n0; h1 = n1; h2 = n2; h3 = n3;
    }
    // epilogue: bodies 121..126 (fo = 121..124, h = 125..128 raw)
    {
        float g0 = (float)h0, g1 = (float)h1;
        EBODY(fo0) EBODY(fo1) EBODY(fo2) EBODY(fo3)   // 121..124
        EBODY(g0)  EBODY(g1)                          // 125, 126
    }

    // K[126,126] = lane 63's E slot after diagonal 252.
    if (lane == 63) {
        float w = (g == 1) ? (-2.0f / 1024.0f) : (1.0f / 1024.0f);
        partial[wid] = w * p1E;
    }
    __syncthreads();
    if (threadIdx.x == 0) atomicAdd(out, partial[0] + partial[1]);
}

extern "C" void kernel_launch(void* const* d_in, const int* in_sizes, int n_in,
                              void* d_out, int out_size, void* d_ws, size_t ws_size,
                              hipStream_t stream) {
    const float* x = (const float*)d_in[0];
    const float* y = (const float*)d_in[1];
    float* out = (float*)d_out;
    (void)in_sizes; (void)n_in; (void)out_size; (void)d_ws; (void)ws_size;

    hipLaunchKernelGGL(zero_kernel, dim3(1), dim3(1), 0, stream, out);
    hipLaunchKernelGGL(sigpde_kernel, dim3(1536), dim3(128), 0, stream, x, y, out);
}

// Round 8
// 76.972 us; speedup vs baseline: 1.1456x; 1.1456x over previous
//
#include <hip/hip_runtime.h>

// Signature-kernel MMD, fused. R8 = R6 (verified 23.9us structure) + ONE delta:
// E-stream via DPP identity eF(k) = wave_shr1(oF(k-1)) (HW-verified correct in
// R7, absmax 0). Grid/block/pipeline/layout identical to R6: 768 blocks x 256
// (4 waves/block, 3 blocks/CU uniform), fp16 row-major binc stride 66 zero-
// padded, convert-then-prefetch order, #pragma unroll 2 (4 bodies/asm iter).
// Out-of-window reads return 0 and/or are multiplied by exactly-zero state
// (verified R2/R3/R4/R6).

constexpr int S2  = 66;     // binc row stride (fp16 elems)
constexpr int PAD = 64;     // front pad (covers negative column offsets)
constexpr int BNA = 4368;   // per-pair buffer (PAD + 63*66 + rear pad, 16B-mult)

__global__ void zero_kernel(float* out) { out[0] = 0.0f; }

__device__ __forceinline__ float dpp_shr1(float v) {
    // result[l] = src[l-1], result[0] = 0
    return __builtin_bit_cast(float,
        __builtin_amdgcn_update_dpp(0, __builtin_bit_cast(int, v), 0x138, 0xF, 0xF, true));
}
__device__ __forceinline__ float dpp_shl1(float v) {
    // result[l] = src[l+1], result[63] = 0
    return __builtin_bit_cast(float,
        __builtin_amdgcn_update_dpp(0, __builtin_bit_cast(int, v), 0x130, 0xF, 0xF, true));
}
__device__ __forceinline__ float dot4(float4 a, float4 b) {
    return a.x * b.x + a.y * b.y + a.z * b.z + a.w * b.w;
}

// Two PDE substeps (antidiagonals 2k-1, 2k); ef/of are RAW binc values.
// State: p1E,p1O (diag d-1), p2E (E diag d-2), up2 (shr1 of O diag d-2),
// oP (previous body's of). Verified R3/R6.
#define BODY(ef, of) {                                 \
    float up1 = dpp_shr1(p1O);                         \
    float cE  = (up1 - up2) + p1E + up2 * (ef);        \
    float cO  = (p1E - p2E) + p1O + p2E * oP;          \
    float nu2 = up1, np2 = p1E;                        \
    p1E = cE; p1O = cO;                                \
    up1 = dpp_shr1(p1O);                               \
    cE  = (up1 - nu2) + p1E + nu2 * (ef);              \
    cO  = (p1E - np2) + p1O + np2 * (of);              \
    up2 = up1; p2E = p1E; p1E = cE; p1O = cO;          \
    oP  = (of); }

// Body with E derived from previous body's O float via DPP (verified R7).
#define EBODY(foCur) {                                 \
    float eF = dpp_shr1(foPrev);                       \
    BODY(eF, foCur)                                    \
    foPrev = (foCur); }

__global__ __launch_bounds__(256) void sigpde_kernel(const float* __restrict__ x,
                                                     const float* __restrict__ y,
                                                     float* __restrict__ out) {
    __shared__ __align__(16) _Float16 binc[4][BNA];   // 34944 B
    __shared__ float4 xs[4][64];                      //  4096 B
    __shared__ float  xxs[4][64];                     //  1024 B
    __shared__ float  partial[4];

    const int lane = threadIdx.x & 63;
    const int wid  = threadIdx.x >> 6;
    const int p = blockIdx.x * 4 + wid;     // 0..3071
    const int g = p >> 10;                  // 0: xx, 1: xy, 2: yy
    const int q = p & 1023;
    const int a = q >> 5, b = q & 31;
    const float* Ab = (g == 2) ? y : x;
    const float* Bb = (g == 0) ? x : y;

    _Float16* bw = &binc[wid][0];

    float4 xa = ((const float4*)(Ab + a * 256))[lane];
    float4 yv = ((const float4*)(Bb + b * 256))[lane];
    xs[wid][lane]  = xa;
    xxs[wid][lane] = dot4(xa, xa);
    const float yy = dot4(yv, yv);

    {   // zero this wave's buffer (pads/gaps must be finite zeros)
        uint4* z = (uint4*)bw;
        const uint4 zz = {0u, 0u, 0u, 0u};
        for (int i = lane; i < BNA / 8; i += 64) z[i] = zz;
    }
    // No barrier: all LDS below is wave-private; same-wave ds ordering
    // is guaranteed via lgkmcnt.

    // Gram + double increments (column = lane), verified R6:
    // binc[u-1][lane] = 0.25*((G[u][l+1]-G[u][l]) - (G[u-1][l+1]-G[u-1][l]))
    float dp = 0.0f;
    #pragma unroll 4
    for (int u = 0; u < 64; ++u) {
        float4 xu = xs[wid][u];            // broadcast read
        float t = xxs[wid][u] + yy - 2.0f * dot4(xu, yv);
        float gv = __expf(-0.5f * t);
        float d = dpp_shl1(gv) - gv;
        if (u > 0) bw[PAD + (u - 1) * S2 + lane] = (_Float16)(0.25f * (d - dp));
        dp = d;
    }

    // Goursat PDE: lane owns rows iE=2l, iO=2l+1; body k = diagonals 2k-1,2k.
    // Single O-stream: body k loads oA[k-1] = binc[l][k-1-l]; the E factor is
    // eF(k) = shr1(oF(k-1)) (lane l-1's O value of the previous body).
    const int rO = (lane <= 62) ? lane : 62;
    const _Float16* oA = bw + PAD + rO * S2 - lane;

    float p1E = (lane == 0) ? 1.0f : 0.0f;  // diag 0 seed: K[0,0]=1
    float p1O = 0.0f, p2E = 0.0f, up2 = 0.0f, oP = 0.0f;
    float foPrev = 0.0f;                    // oF(0): out-of-window -> 0

    // warmup: bodies 1,2 converted; bodies 3,4 in flight (R6 structure)
    _Float16 ho2 = oA[2], ho3 = oA[3];
    float fo0 = (float)oA[0], fo1 = (float)oA[1];

    #pragma unroll 2
    for (int k = 1; k <= 125; k += 2) {
        // convert bodies k+2, k+3 (loaded last iteration)  [R6 order]
        float go2 = (float)ho2, go3 = (float)ho3;
        // prefetch bodies k+4, k+5
        ho2 = oA[k + 3]; ho3 = oA[k + 4];
        // compute bodies k, k+1
        EBODY(fo0)
        EBODY(fo1)
        // rotate pipeline
        fo0 = go2; fo1 = go3;
    }

    // K[126,126] = lane 63's E slot after diagonal 252.
    if (lane == 63) {
        float w = (g == 1) ? (-2.0f / 1024.0f) : (1.0f / 1024.0f);
        partial[wid] = w * p1E;
    }
    __syncthreads();
    if (threadIdx.x == 0) {
        atomicAdd(out, (partial[0] + partial[1]) + (partial[2] + partial[3]));
    }
}

extern "C" void kernel_launch(void* const* d_in, const int* in_sizes, int n_in,
                              void* d_out, int out_size, void* d_ws, size_t ws_size,
                              hipStream_t stream) {
    const float* x = (const float*)d_in[0];
    const float* y = (const float*)d_in[1];
    float* out = (float*)d_out;
    (void)in_sizes; (void)n_in; (void)out_size; (void)d_ws; (void)ws_size;

    hipLaunchKernelGGL(zero_kernel, dim3(1), dim3(1), 0, stream, out);
    hipLaunchKernelGGL(sigpde_kernel, dim3(768), dim3(256), 0, stream, x, y, out);
}